// Round 6
// baseline (382.217 us; speedup 1.0000x reference)
//
#include <hip/hip_runtime.h>

// LearnedRouter: logits = x[T,H] @ W[E,H]^T ; softmax ; top-2.
// T=16384, H=4096, E=8. Output flat: scores[T*8] | weights[T*2] | idx[T*2] (fp32).
//
// R6: maximize per-CU miss-level parallelism. R2/R4/R5 all plateau at
// ~115-120 us because each CU streams its 1 MB x-share at ~8.7 GB/s —
// outstanding-miss limited, not pipe-throughput limited. Changes:
//   * ROWS_PER_WAVE 4 -> 2  (acc 16 + xv 16 + addr ~= 55 VGPR)
//   * __launch_bounds__(1024, 8) -> VGPR cap 64 -> 8 waves/SIMD
//   * grid 512 -> 2 independent blocks/CU (barriers decoupled), 32 waves/CU
// W still served from LDS (2 x 64 KB chunks) keeping the global pipe x-only.

#define ROUTER_H4 1024       // float4 per row (H=4096)
#define ROUTER_E 8
#define ROWS_PER_WAVE 2
#define CHUNK 512            // float4 per expert per chunk (64 KB chunk)
#define NCHUNK (ROUTER_H4 / CHUNK)   // 2

__global__ __launch_bounds__(1024, 8) void learned_router_kernel(
    const float* __restrict__ x, const float* __restrict__ W,
    float* __restrict__ out_scores, float* __restrict__ out_w,
    float* __restrict__ out_idx, int n_rows)
{
    __shared__ float4 wlds[ROUTER_E][CHUNK];   // 64 KB

    const int tid  = (int)threadIdx.x;          // 0..1023
    const int wv   = tid >> 6;                  // wave in block: 0..15
    const int lane = tid & 63;
    const int row0 = (int)blockIdx.x * (16 * ROWS_PER_WAVE) + wv * ROWS_PER_WAVE;

    const float4* __restrict__ x4 = (const float4*)x;
    const float4* __restrict__ W4 = (const float4*)W;

    float acc[ROWS_PER_WAVE][ROUTER_E];
#pragma unroll
    for (int r = 0; r < ROWS_PER_WAVE; ++r)
#pragma unroll
        for (int e = 0; e < ROUTER_E; ++e) acc[r][e] = 0.f;

    for (int c = 0; c < NCHUNK; ++c) {
        // ---- stage 64 KB chunk: 4096 float4 / 1024 threads = 4 each ----
#pragma unroll
        for (int k = 0; k < 4; ++k) {
            const int flat = k * 1024 + tid;        // 0..4095, coalesced
            const int e    = flat >> 9;             // /CHUNK
            const int pos  = flat & (CHUNK - 1);
            wlds[e][pos] = W4[e * ROUTER_H4 + c * CHUNK + pos];
        }
        __syncthreads();

        // ---- compute: 8 barrier-free iters of 64 float4 positions ----
#pragma unroll 2
        for (int inner = 0; inner < CHUNK / 64; ++inner) {
            const int idx  = inner * 64 + lane;
            const int hpos = c * CHUNK + idx;
            float4 xv[ROWS_PER_WAVE];
#pragma unroll
            for (int r = 0; r < ROWS_PER_WAVE; ++r)
                xv[r] = x4[(size_t)(row0 + r) * ROUTER_H4 + hpos];
#pragma unroll
            for (int e = 0; e < ROUTER_E; ++e) {
                const float4 w4 = wlds[e][idx];
#pragma unroll
                for (int r = 0; r < ROWS_PER_WAVE; ++r)
                    acc[r][e] += xv[r].x * w4.x + xv[r].y * w4.y
                               + xv[r].z * w4.z + xv[r].w * w4.w;
            }
        }
        __syncthreads();
    }

    // ---- wave butterfly reduction (64 lanes) ----
#pragma unroll
    for (int off = 32; off > 0; off >>= 1) {
#pragma unroll
        for (int r = 0; r < ROWS_PER_WAVE; ++r)
#pragma unroll
            for (int e = 0; e < ROUTER_E; ++e)
                acc[r][e] += __shfl_xor(acc[r][e], off, 64);
    }

    if (lane == 0) {
#pragma unroll
        for (int r = 0; r < ROWS_PER_WAVE; ++r) {
            const int row = row0 + r;
            float m = acc[r][0];
#pragma unroll
            for (int e = 1; e < ROUTER_E; ++e) m = fmaxf(m, acc[r][e]);
            float p[ROUTER_E];
            float s = 0.f;
#pragma unroll
            for (int e = 0; e < ROUTER_E; ++e) { p[e] = __expf(acc[r][e] - m); s += p[e]; }
            const float inv = 1.f / s;
#pragma unroll
            for (int e = 0; e < ROUTER_E; ++e) p[e] *= inv;

            float4* os = (float4*)(out_scores + (size_t)row * ROUTER_E);
            os[0] = make_float4(p[0], p[1], p[2], p[3]);
            os[1] = make_float4(p[4], p[5], p[6], p[7]);

            // top-2, lowest-index tie-break (matches jax.lax.top_k)
            int i0 = 0;
#pragma unroll
            for (int e = 1; e < ROUTER_E; ++e) if (p[e] > p[i0]) i0 = e;
            int i1 = (i0 == 0) ? 1 : 0;
#pragma unroll
            for (int e = 0; e < ROUTER_E; ++e) if (e != i0 && p[e] > p[i1]) i1 = e;

            *(float2*)(out_w + (size_t)row * 2)   = make_float2(p[i0], p[i1]);
            *(float2*)(out_idx + (size_t)row * 2) = make_float2((float)i0, (float)i1);
        }
    }
}

extern "C" void kernel_launch(void* const* d_in, const int* in_sizes, int n_in,
                              void* d_out, int out_size, void* d_ws, size_t ws_size,
                              hipStream_t stream) {
    const float* x = (const float*)d_in[0];
    const float* W = (const float*)d_in[1];
    const int T = in_sizes[0] / (ROUTER_H4 * 4);     // 16384
    (void)n_in; (void)d_ws; (void)ws_size; (void)out_size;

    float* out = (float*)d_out;
    float* out_scores = out;
    float* out_w   = out + (size_t)T * ROUTER_E;
    float* out_idx = out_w + (size_t)T * 2;

    const int rows_per_block = 16 * ROWS_PER_WAVE;   // 32
    const int grid = (T + rows_per_block - 1) / rows_per_block;  // 512 = 2 blocks/CU
    learned_router_kernel<<<grid, 1024, 0, stream>>>(x, W, out_scores, out_w, out_idx, T);
}